// Round 1
// baseline (305.434 us; speedup 1.0000x reference)
//
#include <hip/hip_runtime.h>
#include <hip/hip_bf16.h>
#include <math.h>

#define HPIX 128
#define WPIX 128
#define NPIX (HPIX*WPIX)   // 16384
#define CCH 64
#define P2 256             // number of windows (16x16)
#define HWIN 64            // pixels per window (8x8)

__device__ __forceinline__ float waveReduceSum(float v){
  #pragma unroll
  for (int m = 32; m >= 1; m >>= 1) v += __shfl_xor(v, m);
  return v;
}

// K1: x1(NHWC,f32) = x + dwconv3x3(x,pos_w,pos_b), from NCHW input.
// grid: 4096 = 256 pixel-groups x 16 channel-groups; block 256 (4 ch x 64 pix)
__global__ void k1_posconv(const float* __restrict__ x, const float* __restrict__ pw,
                           const float* __restrict__ pb, float* __restrict__ x1){
  int tid = threadIdx.x;
  int pl = tid & 63;
  int cl = tid >> 6;
  int pix0 = (blockIdx.x & 255) * 64;
  int cg   = (blockIdx.x >> 8);
  int c = cg*4 + cl;
  int pix = pix0 + pl;
  int y = pix >> 7, xx = pix & 127;
  const float* xc = x + c*NPIX;
  float acc = pb[c];
  #pragma unroll
  for (int dy=0; dy<3; dy++){
    int yy = y+dy-1; if ((unsigned)yy >= (unsigned)HPIX) continue;
    #pragma unroll
    for (int dx=0; dx<3; dx++){
      int x2 = xx+dx-1; if ((unsigned)x2 >= (unsigned)WPIX) continue;
      acc += pw[c*9 + dy*3 + dx] * xc[yy*WPIX + x2];
    }
  }
  __shared__ float lds[4][64];
  lds[cl][pl] = xc[pix] + acc;
  __syncthreads();
  int pp = tid >> 2, cc = tid & 3;
  x1[(pix0+pp)*CCH + cg*4 + cc] = lds[cc][pp];
}

// K2: LN(x1) then qkv = ln @ qkv_w + qkv_b, written window-major [p][r][192].
// wave per pixel; block 256 = 4 waves; grid 4096
__global__ void k2_ln_qkv(const float* __restrict__ x1,
                          const float* __restrict__ g, const float* __restrict__ bb,
                          const float* __restrict__ qw, const float* __restrict__ qb,
                          float* __restrict__ qkv){
  int tid = threadIdx.x;
  int lane = tid & 63;
  int w = tid >> 6;
  int pix = (blockIdx.x << 2) + w;
  __shared__ float lds[4][64];
  float v = x1[pix*CCH + lane];
  float mean = waveReduceSum(v) * (1.f/64.f);
  float d = v - mean;
  float var = waveReduceSum(d*d) * (1.f/64.f);
  lds[w][lane] = d * rsqrtf(var + 1e-6f) * g[lane] + bb[lane];
  __syncthreads();
  int y = pix >> 7, xx = pix & 127;
  int p = (y>>3)*16 + (xx>>3);
  int r = ((y&7)<<3) + (xx&7);
  float* out = qkv + (p*HWIN + r)*192;
  #pragma unroll
  for (int t=0; t<3; t++){
    int co = t*64 + lane;
    float acc = qb[co];
    #pragma unroll 8
    for (int k=0; k<64; k++)
      acc += lds[w][k] * qw[k*192 + co];
    out[co] = acc;
  }
}

// K3: per-window means of q and k. grid 256, block 64 (thread = channel)
__global__ void k3_winmean(const float* __restrict__ qkv,
                           float* __restrict__ qwin, float* __restrict__ kwin){
  int p = blockIdx.x, c = threadIdx.x;
  float sq = 0.f, sk = 0.f;
  for (int r=0; r<HWIN; r++){
    const float* row = qkv + (p*HWIN + r)*192;
    sq += row[c];
    sk += row[64 + c];
  }
  qwin[p*64 + c] = sq * (1.f/64.f);
  kwin[p*64 + c] = sk * (1.f/64.f);
}

// K4: logits[p][q] = qwin[p].kwin[q]; top-4 indices (desc, ties -> lowest index).
// grid 256, block 256
__global__ void k4_topk(const float* __restrict__ qwin, const float* __restrict__ kwin,
                        int* __restrict__ idx){
  int p = blockIdx.x, t = threadIdx.x;
  __shared__ float lg[P2];
  float acc = 0.f;
  for (int c=0; c<64; c++) acc += qwin[p*64 + c] * kwin[t*64 + c];
  lg[t] = acc;
  __syncthreads();
  if (t == 0){
    #pragma unroll
    for (int j=0; j<4; j++){
      float best = -1e30f; int bi = 0;
      for (int i=0; i<P2; i++){ float v = lg[i]; if (v > best){ best = v; bi = i; } }
      idx[p*4 + j] = bi;
      lg[bi] = -1e30f;
    }
  }
}

// K5: attention for (window p, head n). block 64 threads (thread = q pixel), grid 2048.
__global__ void k5_attn(const float* __restrict__ qkv, const int* __restrict__ idx,
                        float* __restrict__ attnout){
  int p = blockIdx.x >> 3, n = blockIdx.x & 7;
  int lane = threadIdx.x;
  __shared__ float Ks[256][8];
  __shared__ float Vs[256][8];
  __shared__ int wsel[4];
  if (lane < 4) wsel[lane] = idx[p*4 + lane];
  __syncthreads();
  int cb = n*8;
  for (int t = lane; t < 256*8; t += 64){
    int k = t >> 3, d = t & 7;
    const float* row = qkv + (wsel[k>>6]*HWIN + (k&63))*192;
    Ks[k][d] = row[64  + cb + d];
    Vs[k][d] = row[128 + cb + d];
  }
  __syncthreads();
  const float* qrow = qkv + (p*HWIN + lane)*192 + cb;
  float q[8];
  #pragma unroll
  for (int d=0; d<8; d++) q[d] = qrow[d] * 0.125f;   // scale = C^-0.5
  float m = -1e30f, l = 0.f, acc[8];
  #pragma unroll
  for (int d=0; d<8; d++) acc[d] = 0.f;
  for (int k=0; k<256; k++){
    float s = 0.f;
    #pragma unroll
    for (int d=0; d<8; d++) s += q[d]*Ks[k][d];
    float mn = fmaxf(m, s);
    float corr = __expf(m - mn);
    float e = __expf(s - mn);
    l = l*corr + e;
    #pragma unroll
    for (int d=0; d<8; d++) acc[d] = acc[d]*corr + e*Vs[k][d];
    m = mn;
  }
  float inv = 1.f / l;
  int yy = (p>>4)*8 + (lane>>3), xx = (p&15)*8 + (lane&7);
  float* orow = attnout + (yy*WPIX + xx)*CCH + cb;
  #pragma unroll
  for (int d=0; d<8; d++) orow[d] = acc[d]*inv;
}

// K6: t = attnout + lepe5x5(v); drf = t @ wo_w + wo_b; x1 += drf (residual).
// wave per pixel; block 256; grid 4096
__global__ void k6_lepe_wo(const float* __restrict__ attnout, const float* __restrict__ qkv,
                           const float* __restrict__ lw, const float* __restrict__ lb,
                           const float* __restrict__ ww, const float* __restrict__ wb,
                           float* __restrict__ x1){
  int tid = threadIdx.x; int lane = tid & 63; int w = tid >> 6;
  int pix = (blockIdx.x << 2) + w;
  int y = pix >> 7, xx = pix & 127;
  int c = lane;
  float acc = lb[c];
  #pragma unroll
  for (int dy=0; dy<5; dy++){
    int yy = y+dy-2; if ((unsigned)yy >= (unsigned)HPIX) continue;
    #pragma unroll
    for (int dx=0; dx<5; dx++){
      int x2 = xx+dx-2; if ((unsigned)x2 >= (unsigned)WPIX) continue;
      int p = (yy>>3)*16 + (x2>>3), r = ((yy&7)<<3) + (x2&7);
      acc += lw[c*25 + dy*5 + dx] * qkv[(p*HWIN + r)*192 + 128 + c];
    }
  }
  __shared__ float lds[4][64];
  lds[w][lane] = attnout[pix*CCH + lane] + acc;
  __syncthreads();
  float o = wb[lane];
  #pragma unroll 8
  for (int k=0; k<64; k++) o += lds[w][k] * ww[k*64 + lane];
  x1[pix*CCH + lane] += o;
}

// K7: y = LN(x2); h = gelu(y@w1+b1); o = h@w2+b2; out(NCHW) = x2 + o.
// wave per pixel; hidden kept in LDS; block 256; grid 4096
__global__ void k7_mlp_out(const float* __restrict__ x2,
                           const float* __restrict__ g, const float* __restrict__ bb,
                           const float* __restrict__ w1, const float* __restrict__ b1,
                           const float* __restrict__ w2, const float* __restrict__ b2,
                           float* __restrict__ out){
  int tid = threadIdx.x; int lane = tid & 63; int w = tid >> 6;
  int pix0 = (blockIdx.x << 2);
  int pix = pix0 + w;
  __shared__ float lds[4][64];
  __shared__ float hid[4][256];
  __shared__ float res[4][64];
  float v = x2[pix*CCH + lane];
  float mean = waveReduceSum(v) * (1.f/64.f);
  float d = v - mean;
  float var = waveReduceSum(d*d) * (1.f/64.f);
  lds[w][lane] = d * rsqrtf(var + 1e-6f) * g[lane] + bb[lane];
  __syncthreads();
  #pragma unroll
  for (int t=0; t<4; t++){
    int co = t*64 + lane;
    float acc = b1[co];
    #pragma unroll 8
    for (int k=0; k<64; k++) acc += lds[w][k] * w1[k*256 + co];
    hid[w][co] = 0.5f*acc*(1.f + erff(acc*0.70710678118654752f));  // exact gelu
  }
  __syncthreads();
  float acc = b2[lane];
  for (int k=0; k<256; k++) acc += hid[w][k] * w2[k*64 + lane];
  res[w][lane] = v + acc;
  __syncthreads();
  // coalesced-ish NCHW write: thread t -> channel t>>2, pixel pix0 + (t&3)
  int ch = tid >> 2, ps = tid & 3;
  out[ch*NPIX + pix0 + ps] = res[ps][ch];
}

extern "C" void kernel_launch(void* const* d_in, const int* in_sizes, int n_in,
                              void* d_out, int out_size, void* d_ws, size_t ws_size,
                              hipStream_t stream) {
  (void)in_sizes; (void)n_in; (void)out_size; (void)ws_size;
  const float* x      = (const float*)d_in[0];
  const float* pos_w  = (const float*)d_in[1];
  const float* pos_b  = (const float*)d_in[2];
  const float* norm_g = (const float*)d_in[3];
  const float* norm_b = (const float*)d_in[4];
  const float* qkv_w  = (const float*)d_in[5];
  const float* qkv_b  = (const float*)d_in[6];
  const float* wo_w   = (const float*)d_in[7];
  const float* wo_b   = (const float*)d_in[8];
  const float* lepe_w = (const float*)d_in[9];
  const float* lepe_b = (const float*)d_in[10];
  const float* mlp_w1 = (const float*)d_in[11];
  const float* mlp_b1 = (const float*)d_in[12];
  const float* mlp_w2 = (const float*)d_in[13];
  const float* mlp_b2 = (const float*)d_in[14];
  float* out = (float*)d_out;

  char* ws = (char*)d_ws;
  float* x1      = (float*)(ws);                          // 4 MB  (becomes x2)
  float* qkv     = (float*)(ws + (4u<<20));               // 12 MB [p][r][192]
  float* qwin    = (float*)(ws + (16u<<20));              // 64 KB
  float* kwin    = (float*)(ws + (16u<<20) + (64u<<10));  // 64 KB
  int*   idx     = (int*)  (ws + (16u<<20) + (128u<<10)); // 4 KB
  float* attnout = (float*)(ws + (17u<<20));              // 4 MB (NHWC)

  hipLaunchKernelGGL(k1_posconv, dim3(4096), dim3(256), 0, stream, x, pos_w, pos_b, x1);
  hipLaunchKernelGGL(k2_ln_qkv,  dim3(4096), dim3(256), 0, stream, x1, norm_g, norm_b, qkv_w, qkv_b, qkv);
  hipLaunchKernelGGL(k3_winmean, dim3(256),  dim3(64),  0, stream, qkv, qwin, kwin);
  hipLaunchKernelGGL(k4_topk,    dim3(256),  dim3(256), 0, stream, qwin, kwin, idx);
  hipLaunchKernelGGL(k5_attn,    dim3(2048), dim3(64),  0, stream, qkv, idx, attnout);
  hipLaunchKernelGGL(k6_lepe_wo, dim3(4096), dim3(256), 0, stream, attnout, qkv, lepe_w, lepe_b, wo_w, wo_b, x1);
  hipLaunchKernelGGL(k7_mlp_out, dim3(4096), dim3(256), 0, stream, x1, norm_g, norm_b, mlp_w1, mlp_b1, mlp_w2, mlp_b2, out);
}

// Round 2
// 276.695 us; speedup vs baseline: 1.1039x; 1.1039x over previous
//
#include <hip/hip_runtime.h>
#include <hip/hip_bf16.h>
#include <math.h>

#define HPIX 128
#define WPIX 128
#define NPIX (HPIX*WPIX)   // 16384
#define CCH 64
#define P2 256             // number of windows (16x16)
#define HWIN 64            // pixels per window (8x8)

__device__ __forceinline__ float waveReduceSum(float v){
  #pragma unroll
  for (int m = 32; m >= 1; m >>= 1) v += __shfl_xor(v, m);
  return v;
}

// K1: x1(NHWC,f32) = x + dwconv3x3(x,pos_w,pos_b), from NCHW input.
__global__ void k1_posconv(const float* __restrict__ x, const float* __restrict__ pw,
                           const float* __restrict__ pb, float* __restrict__ x1){
  int tid = threadIdx.x;
  int pl = tid & 63;
  int cl = tid >> 6;
  int pix0 = (blockIdx.x & 255) * 64;
  int cg   = (blockIdx.x >> 8);
  int c = cg*4 + cl;
  int pix = pix0 + pl;
  int y = pix >> 7, xx = pix & 127;
  const float* xc = x + c*NPIX;
  float acc = pb[c];
  #pragma unroll
  for (int dy=0; dy<3; dy++){
    int yy = y+dy-1; if ((unsigned)yy >= (unsigned)HPIX) continue;
    #pragma unroll
    for (int dx=0; dx<3; dx++){
      int x2 = xx+dx-1; if ((unsigned)x2 >= (unsigned)WPIX) continue;
      acc += pw[c*9 + dy*3 + dx] * xc[yy*WPIX + x2];
    }
  }
  __shared__ float lds[4][64];
  lds[cl][pl] = xc[pix] + acc;
  __syncthreads();
  int pp = tid >> 2, cc = tid & 3;
  x1[(pix0+pp)*CCH + cg*4 + cc] = lds[cc][pp];
}

// K2: LN + qkv. 32 pixels/block; wave w -> 48 output cols; lane = (pix 0-31, co-half).
// Weight reads amortized 32x via lnT broadcast. grid 512, block 256.
__global__ void k2_ln_qkv(const float* __restrict__ x1,
                          const float* __restrict__ g, const float* __restrict__ bb,
                          const float* __restrict__ qw, const float* __restrict__ qb,
                          float* __restrict__ qkv){
  __shared__ float lnT[64][33];   // [ch][pix_local]
  int tid = threadIdx.x, w = tid >> 6, lane = tid & 63;
  int pix0 = blockIdx.x * 32;
  for (int i=0; i<8; i++){
    int pl = w*8 + i, pix = pix0 + pl;
    float v = x1[pix*CCH + lane];
    float mean = waveReduceSum(v) * (1.f/64.f);
    float d = v - mean;
    float var = waveReduceSum(d*d) * (1.f/64.f);
    lnT[lane][pl] = d * rsqrtf(var + 1e-6f) * g[lane] + bb[lane];
  }
  __syncthreads();
  int pl = lane & 31, ch = lane >> 5;
  int co0 = w*48 + ch*24;
  float acc[24];
  #pragma unroll
  for (int j=0; j<24; j++) acc[j] = qb[co0+j];
  for (int k=0; k<64; k++){
    float a = lnT[k][pl];
    const float* wr = qw + k*192 + co0;
    #pragma unroll
    for (int j4=0; j4<6; j4++){
      float4 wv = *(const float4*)(wr + j4*4);
      acc[j4*4+0] += a*wv.x; acc[j4*4+1] += a*wv.y;
      acc[j4*4+2] += a*wv.z; acc[j4*4+3] += a*wv.w;
    }
  }
  int pix = pix0 + pl;
  int y = pix >> 7, xx = pix & 127;
  int p = (y>>3)*16 + (xx>>3);
  int r = ((y&7)<<3) + (xx&7);
  float* o = qkv + (p*HWIN + r)*192 + co0;
  #pragma unroll
  for (int j=0; j<24; j+=4){
    float4 s; s.x=acc[j]; s.y=acc[j+1]; s.z=acc[j+2]; s.w=acc[j+3];
    *(float4*)(o + j) = s;
  }
}

// K3: per-window means of q and k. grid 256, block 256 (4-way row split).
__global__ void k3_winmean(const float* __restrict__ qkv,
                           float* __restrict__ qwin, float* __restrict__ kwin){
  int p = blockIdx.x;
  int tid = threadIdx.x, rq = tid >> 6, c = tid & 63;
  float sq = 0.f, sk = 0.f;
  for (int r = rq*16; r < rq*16+16; r++){
    const float* row = qkv + (p*HWIN + r)*192;
    sq += row[c];
    sk += row[64 + c];
  }
  __shared__ float s1[4][64], s2[4][64];
  s1[rq][c] = sq; s2[rq][c] = sk;
  __syncthreads();
  if (tid < 64){
    float a = s1[0][c]+s1[1][c]+s1[2][c]+s1[3][c];
    float b = s2[0][c]+s2[1][c]+s2[2][c]+s2[3][c];
    qwin[p*64 + c] = a*(1.f/64.f);
    kwin[p*64 + c] = b*(1.f/64.f);
  }
}

// K4: logits + top-4 (desc, ties -> lowest index), block-parallel selection.
__global__ void k4_topk(const float* __restrict__ qwin, const float* __restrict__ kwin,
                        int* __restrict__ idx){
  int p = blockIdx.x, t = threadIdx.x;
  int w = t >> 6, lane = t & 63;
  __shared__ float lg[P2];
  __shared__ float wv[4]; __shared__ int wi[4];
  const float* qr = qwin + p*64;
  const float* kr = kwin + t*64;
  float acc = 0.f;
  for (int c=0; c<64; c++) acc += qr[c]*kr[c];
  lg[t] = acc;
  __syncthreads();
  for (int j=0; j<4; j++){
    float v = lg[t]; int i = t;
    #pragma unroll
    for (int m=32; m>=1; m>>=1){
      float ov = __shfl_xor(v, m); int oi = __shfl_xor(i, m);
      if (ov > v || (ov == v && oi < i)){ v = ov; i = oi; }
    }
    if (lane == 0){ wv[w] = v; wi[w] = i; }
    __syncthreads();
    if (t == 0){
      float bv = wv[0]; int bi = wi[0];
      #pragma unroll
      for (int u=1; u<4; u++)
        if (wv[u] > bv || (wv[u] == bv && wi[u] < bi)){ bv = wv[u]; bi = wi[u]; }
      idx[p*4 + j] = bi;
      lg[bi] = -1e30f;
    }
    __syncthreads();
  }
}

// K5: attention for (window p, head n). 4 waves split the 256 keys; flash merge.
// grid 2048, block 256.
__global__ void k5_attn(const float* __restrict__ qkv, const int* __restrict__ idx,
                        float* __restrict__ attnout){
  int p = blockIdx.x >> 3, n = blockIdx.x & 7;
  int tid = threadIdx.x, w = tid >> 6, lane = tid & 63;
  __shared__ float Ks[256][8];
  __shared__ float Vs[256][8];
  __shared__ int wsel[4];
  __shared__ float pm[4][64], pls[4][64], pacc[4][64][9];
  if (tid < 4) wsel[tid] = idx[p*4 + tid];
  __syncthreads();
  int cb = n*8;
  for (int u = tid; u < 512; u += 256){
    int k = u >> 1, h = u & 1;
    const float* row = qkv + (wsel[k>>6]*HWIN + (k&63))*192;
    *(float4*)&Ks[k][h*4] = *(const float4*)(row + 64  + cb + h*4);
    *(float4*)&Vs[k][h*4] = *(const float4*)(row + 128 + cb + h*4);
  }
  __syncthreads();
  const float* qrow = qkv + (p*HWIN + lane)*192 + cb;
  float q[8];
  #pragma unroll
  for (int d=0; d<8; d++) q[d] = qrow[d] * 0.125f;
  float m = -1e30f, l = 0.f, acc[8];
  #pragma unroll
  for (int d=0; d<8; d++) acc[d] = 0.f;
  for (int k = w*64; k < w*64+64; k++){
    float4 ka = *(float4*)&Ks[k][0];
    float4 kb = *(float4*)&Ks[k][4];
    float s = q[0]*ka.x + q[1]*ka.y + q[2]*ka.z + q[3]*ka.w
            + q[4]*kb.x + q[5]*kb.y + q[6]*kb.z + q[7]*kb.w;
    float mn = fmaxf(m, s);
    float corr = __expf(m - mn);
    float e = __expf(s - mn);
    l = l*corr + e;
    float4 va = *(float4*)&Vs[k][0];
    float4 vb = *(float4*)&Vs[k][4];
    acc[0]=acc[0]*corr+e*va.x; acc[1]=acc[1]*corr+e*va.y;
    acc[2]=acc[2]*corr+e*va.z; acc[3]=acc[3]*corr+e*va.w;
    acc[4]=acc[4]*corr+e*vb.x; acc[5]=acc[5]*corr+e*vb.y;
    acc[6]=acc[6]*corr+e*vb.z; acc[7]=acc[7]*corr+e*vb.w;
    m = mn;
  }
  pm[w][lane] = m; pls[w][lane] = l;
  #pragma unroll
  for (int d=0; d<8; d++) pacc[w][lane][d] = acc[d];
  __syncthreads();
  if (w == 0){
    float M = pm[0][lane];
    #pragma unroll
    for (int u=1; u<4; u++) M = fmaxf(M, pm[u][lane]);
    float L = 0.f, o[8];
    #pragma unroll
    for (int d=0; d<8; d++) o[d] = 0.f;
    #pragma unroll
    for (int u=0; u<4; u++){
      float c = __expf(pm[u][lane] - M);
      L += c * pls[u][lane];
      #pragma unroll
      for (int d=0; d<8; d++) o[d] += c * pacc[u][lane][d];
    }
    float inv = 1.f / L;
    int yy = (p>>4)*8 + (lane>>3), xx = (p&15)*8 + (lane&7);
    float* orow = attnout + (yy*WPIX + xx)*CCH + cb;
    #pragma unroll
    for (int d=0; d<8; d++) orow[d] = o[d]*inv;
  }
}

// K6: t = attnout + lepe5x5(v); x1 += t @ wo_w + wo_b. 32 pixels/block.
// Phase A: lepe per-pixel (lane=channel) -> LDS transposed. Phase B: wo with reuse.
__global__ void k6_lepe_wo(const float* __restrict__ attnout, const float* __restrict__ qkv,
                           const float* __restrict__ lw, const float* __restrict__ lb,
                           const float* __restrict__ ww, const float* __restrict__ wb,
                           float* __restrict__ x1){
  __shared__ float tT[64][33];   // [ch][pix_local]
  int tid = threadIdx.x, w = tid >> 6, lane = tid & 63;
  int pix0 = blockIdx.x * 32;
  for (int i=0; i<8; i++){
    int pl = w*8 + i, pix = pix0 + pl;
    int y = pix >> 7, xx = pix & 127;
    float acc = lb[lane];
    #pragma unroll
    for (int dy=0; dy<5; dy++){
      int yy = y+dy-2; if ((unsigned)yy >= (unsigned)HPIX) continue;
      #pragma unroll
      for (int dx=0; dx<5; dx++){
        int x2 = xx+dx-2; if ((unsigned)x2 >= (unsigned)WPIX) continue;
        int pp = (yy>>3)*16 + (x2>>3), rr = ((yy&7)<<3) + (x2&7);
        acc += lw[lane*25 + dy*5 + dx] * qkv[(pp*HWIN + rr)*192 + 128 + lane];
      }
    }
    tT[lane][pl] = attnout[pix*CCH + lane] + acc;
  }
  __syncthreads();
  int pl = lane & 31, ch = lane >> 5;
  int co0 = w*16 + ch*8;
  float acc2[8];
  #pragma unroll
  for (int j=0; j<8; j++) acc2[j] = wb[co0+j];
  for (int k=0; k<64; k++){
    float a = tT[k][pl];
    const float* wr = ww + k*64 + co0;
    float4 u0 = *(const float4*)(wr);
    float4 u1 = *(const float4*)(wr + 4);
    acc2[0]+=a*u0.x; acc2[1]+=a*u0.y; acc2[2]+=a*u0.z; acc2[3]+=a*u0.w;
    acc2[4]+=a*u1.x; acc2[5]+=a*u1.y; acc2[6]+=a*u1.z; acc2[7]+=a*u1.w;
  }
  int pix = pix0 + pl;
  float* xb = x1 + pix*CCH + co0;
  float4 r0 = *(float4*)(xb);
  float4 r1 = *(float4*)(xb + 4);
  r0.x+=acc2[0]; r0.y+=acc2[1]; r0.z+=acc2[2]; r0.w+=acc2[3];
  r1.x+=acc2[4]; r1.y+=acc2[5]; r1.z+=acc2[6]; r1.w+=acc2[7];
  *(float4*)(xb) = r0;
  *(float4*)(xb + 4) = r1;
}

// K7: y=LN(x2); h=gelu(y@w1+b1); o=h@w2+b2; out(NCHW)=x2+o. 32 pixels/block.
// fc1: wave w -> 64 hidden cols (lane: pix, 32-col half). fc2: wave w -> 16 out cols.
__global__ void k7_mlp_out(const float* __restrict__ x2,
                           const float* __restrict__ g, const float* __restrict__ bb,
                           const float* __restrict__ w1, const float* __restrict__ b1,
                           const float* __restrict__ w2, const float* __restrict__ b2,
                           float* __restrict__ out){
  __shared__ float lnT[64][33];
  __shared__ float x2T[64][33];
  __shared__ float hidT[256][33];
  int tid = threadIdx.x, w = tid >> 6, lane = tid & 63;
  int pix0 = blockIdx.x * 32;
  for (int i=0; i<8; i++){
    int pl = w*8 + i, pix = pix0 + pl;
    float v = x2[pix*CCH + lane];
    float mean = waveReduceSum(v) * (1.f/64.f);
    float d = v - mean;
    float var = waveReduceSum(d*d) * (1.f/64.f);
    x2T[lane][pl] = v;
    lnT[lane][pl] = d * rsqrtf(var + 1e-6f) * g[lane] + bb[lane];
  }
  __syncthreads();
  int pl = lane & 31, ch = lane >> 5;
  {
    int co0 = w*64 + ch*32;
    float acc[32];
    #pragma unroll
    for (int j=0; j<32; j++) acc[j] = b1[co0+j];
    for (int k=0; k<64; k++){
      float a = lnT[k][pl];
      const float* wr = w1 + k*256 + co0;
      #pragma unroll
      for (int j4=0; j4<8; j4++){
        float4 wv = *(const float4*)(wr + j4*4);
        acc[j4*4+0] += a*wv.x; acc[j4*4+1] += a*wv.y;
        acc[j4*4+2] += a*wv.z; acc[j4*4+3] += a*wv.w;
      }
    }
    #pragma unroll
    for (int j=0; j<32; j++){
      float h = acc[j];
      h = 0.5f*h*(1.f + erff(h*0.70710678118654752f));
      hidT[co0+j][pl] = h;
    }
  }
  __syncthreads();
  {
    int j0 = w*16 + ch*8;
    float acc2[8];
    #pragma unroll
    for (int j=0; j<8; j++) acc2[j] = b2[j0+j];
    for (int k=0; k<256; k++){
      float a = hidT[k][pl];
      const float* wr = w2 + k*64 + j0;
      float4 u0 = *(const float4*)(wr);
      float4 u1 = *(const float4*)(wr + 4);
      acc2[0]+=a*u0.x; acc2[1]+=a*u0.y; acc2[2]+=a*u0.z; acc2[3]+=a*u0.w;
      acc2[4]+=a*u1.x; acc2[5]+=a*u1.y; acc2[6]+=a*u1.z; acc2[7]+=a*u1.w;
    }
    int pix = pix0 + pl;
    #pragma unroll
    for (int j=0; j<8; j++)
      out[(j0+j)*NPIX + pix] = x2T[j0+j][pl] + acc2[j];
  }
}

extern "C" void kernel_launch(void* const* d_in, const int* in_sizes, int n_in,
                              void* d_out, int out_size, void* d_ws, size_t ws_size,
                              hipStream_t stream) {
  (void)in_sizes; (void)n_in; (void)out_size; (void)ws_size;
  const float* x      = (const float*)d_in[0];
  const float* pos_w  = (const float*)d_in[1];
  const float* pos_b  = (const float*)d_in[2];
  const float* norm_g = (const float*)d_in[3];
  const float* norm_b = (const float*)d_in[4];
  const float* qkv_w  = (const float*)d_in[5];
  const float* qkv_b  = (const float*)d_in[6];
  const float* wo_w   = (const float*)d_in[7];
  const float* wo_b   = (const float*)d_in[8];
  const float* lepe_w = (const float*)d_in[9];
  const float* lepe_b = (const float*)d_in[10];
  const float* mlp_w1 = (const float*)d_in[11];
  const float* mlp_b1 = (const float*)d_in[12];
  const float* mlp_w2 = (const float*)d_in[13];
  const float* mlp_b2 = (const float*)d_in[14];
  float* out = (float*)d_out;

  char* ws = (char*)d_ws;
  float* x1      = (float*)(ws);                          // 4 MB  (becomes x2)
  float* qkv     = (float*)(ws + (4u<<20));               // 12 MB [p][r][192]
  float* qwin    = (float*)(ws + (16u<<20));              // 64 KB
  float* kwin    = (float*)(ws + (16u<<20) + (64u<<10));  // 64 KB
  int*   idx     = (int*)  (ws + (16u<<20) + (128u<<10)); // 4 KB
  float* attnout = (float*)(ws + (17u<<20));              // 4 MB (NHWC)

  hipLaunchKernelGGL(k1_posconv, dim3(4096), dim3(256), 0, stream, x, pos_w, pos_b, x1);
  hipLaunchKernelGGL(k2_ln_qkv,  dim3(512),  dim3(256), 0, stream, x1, norm_g, norm_b, qkv_w, qkv_b, qkv);
  hipLaunchKernelGGL(k3_winmean, dim3(256),  dim3(256), 0, stream, qkv, qwin, kwin);
  hipLaunchKernelGGL(k4_topk,    dim3(256),  dim3(256), 0, stream, qwin, kwin, idx);
  hipLaunchKernelGGL(k5_attn,    dim3(2048), dim3(256), 0, stream, qkv, idx, attnout);
  hipLaunchKernelGGL(k6_lepe_wo, dim3(512),  dim3(256), 0, stream, attnout, qkv, lepe_w, lepe_b, wo_w, wo_b, x1);
  hipLaunchKernelGGL(k7_mlp_out, dim3(512),  dim3(256), 0, stream, x1, norm_g, norm_b, mlp_w1, mlp_b1, mlp_w2, mlp_b2, out);
}